// Round 6
// baseline (900.566 us; speedup 1.0000x reference)
//
#include <hip/hip_runtime.h>
#include <cstdio>

// ---------------------------------------------------------------------------
// BiLSTM  B=64, T=512, D=256, H=256
//   P0: x -> bf16; Wih -> bf16 with gate-permuted rows (n -> (n&255)*4+(n>>8));
//       permuted bias vectors; Whh -> int8 wq4[d][kc][j][gate]
//   P1: MFMA bf16 GEMM (contiguous epilogue) -> xproj[d][b*512+t][j*4+gate]
//   P2: recurrence: 128 WGs (64 batch x 2 dir) x 512 thr. Thread (p,j) owns
//       gate rows {2p,2p+1} of unit j: 128 int8-packed dwords parked in
//       AGPRs via explicit v_accvgpr_write (volatile asm, "a" constraint).
//       R1-R5 lesson: the VGPR allocator spills any large loop-crossing
//       live set to scratch -> 32 MB/step L2 traffic -> 472 us floor. AGPRs
//       are the half of the unified register file RA never competes for.
//       h int8 in double-buffered LDS; lgkm-only barriers.
// ---------------------------------------------------------------------------

typedef unsigned short ushort_t;
typedef __attribute__((ext_vector_type(8))) short short8;
typedef __attribute__((ext_vector_type(4))) float f32x4;

__device__ __forceinline__ ushort_t f2bf(float f) {
    union { float f; unsigned u; } v; v.f = f;
    unsigned r = v.u + 0x7fffu + ((v.u >> 16) & 1u);
    return (ushort_t)(r >> 16);
}
__device__ __forceinline__ float bf2f(ushort_t h) {
    union { unsigned u; float f; } v; v.u = ((unsigned)h) << 16;
    return v.f;
}

__device__ __forceinline__ float fexp2(float x) {
#if __has_builtin(__builtin_amdgcn_exp2f)
    return __builtin_amdgcn_exp2f(x);
#else
    return exp2f(x);
#endif
}
__device__ __forceinline__ float frcp(float x) {
#if __has_builtin(__builtin_amdgcn_rcpf)
    return __builtin_amdgcn_rcpf(x);
#else
    return 1.0f / x;
#endif
}
__device__ __forceinline__ float fsig(float x) {
    return frcp(1.0f + fexp2(-1.44269504089f * x));
}
__device__ __forceinline__ float ftanh(float x) {
    float e = fexp2(2.88539008178f * x);
    return 1.0f - 2.0f * frcp(e + 1.0f);
}

__device__ __forceinline__ int dot4(int a, int b, int c) {
#if __has_builtin(__builtin_amdgcn_sdot4)
    return __builtin_amdgcn_sdot4(a, b, c, false);
#else
    int r = c;
    r += ((a << 24) >> 24) * ((b << 24) >> 24);
    r += ((a << 16) >> 24) * ((b << 16) >> 24);
    r += ((a << 8) >> 24) * ((b << 8) >> 24);
    r += (a >> 24) * (b >> 24);
    return r;
#endif
}

// Park a dword in an AGPR (executes exactly once; volatile => not sinkable).
__device__ __forceinline__ int apark(int v) {
    int a;
    asm volatile("v_accvgpr_write_b32 %0, %1" : "=a"(a) : "v"(v));
    return a;
}
// Retrieve from AGPR into a VGPR (volatile => cannot be hoisted out of the
// time loop into a long-lived VGPR, which is what caused the R1-R5 spills).
__device__ __forceinline__ int aread(int a) {
    int v;
    asm volatile("v_accvgpr_read_b32 %0, %1" : "=v"(v) : "a"(a));
    return v;
}

// LDS-only barrier: drain lgkm (LDS ops) but NOT vmcnt.
__device__ __forceinline__ void lds_barrier() {
    asm volatile("s_waitcnt lgkmcnt(0)\n\ts_barrier" ::: "memory");
}

// ---------------------------------------------------------------------------
// P0a: fp32 -> bf16 (n multiple of 4)
__global__ __launch_bounds__(256) void k_f2bf(const float* __restrict__ in,
                                              ushort_t* __restrict__ out, int n) {
    int i = (blockIdx.x * 256 + threadIdx.x) * 4;
    if (i + 3 < n) {
        float4 v = *(const float4*)&in[i];
        ushort4 o;
        o.x = f2bf(v.x); o.y = f2bf(v.y); o.z = f2bf(v.z); o.w = f2bf(v.w);
        *(ushort4*)&out[i] = o;
    }
}

// P0b: Wih fp32 -> bf16 with gate-permuted ROW order:
//   dst[d][(n&255)*4 + (n>>8)][k] = src_d[n][k]
__global__ __launch_bounds__(256) void k_wih(const float* __restrict__ wihf,
                                             const float* __restrict__ wihb,
                                             ushort_t* __restrict__ dst) {
    int d = blockIdx.y;
    int n = blockIdx.x * 4 + (threadIdx.x >> 6);   // 0..1023
    int l = threadIdx.x & 63;
    const float* src = (d ? wihb : wihf) + (size_t)n * 256;
    float4 v = *(const float4*)&src[l * 4];
    int np = (n & 255) * 4 + (n >> 8);
    ushort4 o;
    o.x = f2bf(v.x); o.y = f2bf(v.y); o.z = f2bf(v.z); o.w = f2bf(v.w);
    *(ushort4*)&dst[((size_t)d * 1024 + np) * 256 + l * 4] = o;
}

// P0c: permuted bias vectors bv[d][(n&255)*4 + (n>>8)] = bih_d[n] + bhh_d[n]
__global__ __launch_bounds__(256) void k_bias(const float* __restrict__ bihf,
                                              const float* __restrict__ bhhf,
                                              const float* __restrict__ bihb,
                                              const float* __restrict__ bhhb,
                                              float* __restrict__ bv) {
    int i = blockIdx.x * 256 + threadIdx.x;   // 0..2047
    int d = i >> 10, n = i & 1023;
    float s = d ? (bihb[n] + bhhb[n]) : (bihf[n] + bhhf[n]);
    bv[d * 1024 + (n & 255) * 4 + (n >> 8)] = s;
}

// P0d: quantize Whh rows to int8.
// wq4[d*65536 + kc*1024 + j*4 + gate], kc=k/4, j=row&255, gate=row>>8.
__global__ __launch_bounds__(256) void k_quant(const float* __restrict__ whhf,
                                               const float* __restrict__ whhb,
                                               int* __restrict__ wq4,
                                               float* __restrict__ fscale4) {
    int rowg = blockIdx.x * 4 + (threadIdx.x >> 6);   // 0..2047
    int l = threadIdx.x & 63;                          // = kc
    int d = rowg >> 10;
    int row = rowg & 1023;
    const float* W = (d ? whhb : whhf) + (size_t)row * 256;
    float4 v = *(const float4*)&W[l * 4];
    float m = fmaxf(fmaxf(fabsf(v.x), fabsf(v.y)), fmaxf(fabsf(v.z), fabsf(v.w)));
    #pragma unroll
    for (int off = 32; off > 0; off >>= 1) m = fmaxf(m, __shfl_xor(m, off));
    float inv = (m > 0.0f) ? (127.0f / m) : 0.0f;
    int q0 = __float2int_rn(v.x * inv);
    int q1 = __float2int_rn(v.y * inv);
    int q2 = __float2int_rn(v.z * inv);
    int q3 = __float2int_rn(v.w * inv);
    q0 = min(127, max(-127, q0)); q1 = min(127, max(-127, q1));
    q2 = min(127, max(-127, q2)); q3 = min(127, max(-127, q3));
    int packed = (q0 & 255) | ((q1 & 255) << 8) | ((q2 & 255) << 16) | ((q3 & 255) << 24);
    int j = row & 255, gate = row >> 8;
    wq4[d * 65536 + l * 1024 + j * 4 + gate] = packed;
    if (l == 0) fscale4[d * 1024 + j * 4 + gate] = m / (127.0f * 127.0f);
}

// ---------------------------------------------------------------------------
// P1: bf16 GEMM (contiguous epilogue; B rows pre-permuted).
#define LDSOFF(r, kc) ((r) * 32 + ((((kc) + ((r) >> 1)) & 3) * 8))

__global__ __launch_bounds__(256) void k_gemm(const ushort_t* __restrict__ A,
                                              const ushort_t* __restrict__ Bw,
                                              const float* __restrict__ biasv,
                                              ushort_t* __restrict__ Xp) {
    const int dir = blockIdx.z;
    const ushort_t* Bmat = Bw + dir * 262144;
    const float* bv = biasv + dir * 1024;
    ushort_t* C = Xp + (size_t)dir * 33554432;
    const int tn = blockIdx.x;   // 0..7
    const int tm = blockIdx.y;   // 0..255
    const int tid = threadIdx.x;
    const int w = tid >> 6, l = tid & 63;
    const int wm = w & 1, wn = w >> 1;

    __shared__ ushort_t As[128 * 32];
    __shared__ ushort_t Bs[128 * 32];

    f32x4 acc[4][4];
    #pragma unroll
    for (int i = 0; i < 4; i++)
        #pragma unroll
        for (int jj = 0; jj < 4; jj++) acc[i][jj] = (f32x4){0.f, 0.f, 0.f, 0.f};

    const int r0 = tid >> 2, c0 = tid & 3;
    const int r1 = (tid + 256) >> 2, c1 = tid & 3;

    for (int kb = 0; kb < 8; kb++) {
        __syncthreads();
        {
            short8 a0 = *(const short8*)&A[((size_t)(tm * 128 + r0)) * 256 + kb * 32 + c0 * 8];
            short8 a1 = *(const short8*)&A[((size_t)(tm * 128 + r1)) * 256 + kb * 32 + c1 * 8];
            short8 b0 = *(const short8*)&Bmat[((size_t)(tn * 128 + r0)) * 256 + kb * 32 + c0 * 8];
            short8 b1 = *(const short8*)&Bmat[((size_t)(tn * 128 + r1)) * 256 + kb * 32 + c1 * 8];
            *(short8*)&As[LDSOFF(r0, c0)] = a0;
            *(short8*)&As[LDSOFF(r1, c1)] = a1;
            *(short8*)&Bs[LDSOFF(r0, c0)] = b0;
            *(short8*)&Bs[LDSOFF(r1, c1)] = b1;
        }
        __syncthreads();
        short8 af[4], bfr[4];
        const int q = l >> 4;
        #pragma unroll
        for (int mt = 0; mt < 4; mt++) {
            int rr = wm * 64 + mt * 16 + (l & 15);
            af[mt] = *(const short8*)&As[LDSOFF(rr, q)];
        }
        #pragma unroll
        for (int nt = 0; nt < 4; nt++) {
            int rr = wn * 64 + nt * 16 + (l & 15);
            bfr[nt] = *(const short8*)&Bs[LDSOFF(rr, q)];
        }
        #pragma unroll
        for (int mt = 0; mt < 4; mt++)
            #pragma unroll
            for (int nt = 0; nt < 4; nt++)
                acc[mt][nt] = __builtin_amdgcn_mfma_f32_16x16x32_bf16(
                    af[mt], bfr[nt], acc[mt][nt], 0, 0, 0);
    }
    #pragma unroll
    for (int nt = 0; nt < 4; nt++) {
        int n = tn * 128 + wn * 64 + nt * 16 + (l & 15);
        float bn = bv[n];
        #pragma unroll
        for (int mt = 0; mt < 4; mt++) {
            #pragma unroll
            for (int rr = 0; rr < 4; rr++) {
                int m = tm * 128 + wm * 64 + mt * 16 + (l >> 4) * 4 + rr;
                C[(size_t)m * 1024 + n] = f2bf(acc[mt][nt][rr] + bn);
            }
        }
    }
}

// ---------------------------------------------------------------------------
// P2: recurrence. grid (64 batch, 2 dir) x 512 threads.
// Thread (p = tid>>8, j = tid&255) owns gate rows {2p, 2p+1} of unit j.
// p=0 -> gates i,f (and owns c[j], h[j]); p=1 -> gates g,o.
__device__ __forceinline__ int time_idx(int s, int len, int d) {
    int sc = (s < len - 1) ? s : (len - 1);
    return (d == 0) ? sc : (len - 1 - sc);
}

__global__ __launch_bounds__(512, 2)
__attribute__((amdgpu_waves_per_eu(2, 2)))
void k_rec(const ushort_t* __restrict__ xproj,
           const int* __restrict__ wq4,
           const float* __restrict__ fscale4,
           const int* __restrict__ lens,
           float* __restrict__ out) {
    const int b = blockIdx.x, d = blockIdx.y;
    const int tid = threadIdx.x;
    const int j = tid & 255, p = tid >> 8;
    int len = lens[b];
    if (len < 1) len = 1;
    if (len > 512) len = 512;
    const ushort_t* xp = xproj + ((size_t)d * 64 + b) * 524288;  // 512*1024
    const int* wq = wq4 + d * 65536;
    float2 fr = *(const float2*)&fscale4[d * 1024 + j * 4 + p * 2];

    // 128 weight dwords parked in AGPRs. Chip-wide this is 512thr*512B =
    // 256 KB/CU = the accumulation half of the unified register file.
    int wa[64], wb[64];
    #pragma unroll
    for (int kc = 0; kc < 64; kc++) {
        int2 v = *(const int2*)&wq[kc * 1024 + j * 4 + p * 2];
        wa[kc] = apark(v.x);
        wb[kc] = apark(v.y);
    }

    __shared__ int h8[2][64] __attribute__((aligned(16)));
    __shared__ float gA[256], oA[256];
    if (tid < 64) h8[0][tid] = 0;

    // zero-fill this direction's half for t in [len, 512)
    {
        float4 z = {0.f, 0.f, 0.f, 0.f};
        int total4 = (512 - len) * 64;
        for (int i = tid; i < total4; i += 512) {
            int t = len + (i >> 6);
            int c4 = i & 63;
            *(float4*)&out[((size_t)b * 512 + t) * 512 + d * 256 + c4 * 4] = z;
        }
    }
    __syncthreads();

    float c_state = 0.0f;
    unsigned xv0 = *(const unsigned*)&xp[(size_t)time_idx(0, len, d) * 1024 + j * 4 + p * 2];
    unsigned xv1 = *(const unsigned*)&xp[(size_t)time_idx(1, len, d) * 1024 + j * 4 + p * 2];

    for (int s = 0; s < len; s++) {
        unsigned xc = xv0;
        xv0 = xv1;
        unsigned xn = *(const unsigned*)&xp[(size_t)time_idx(s + 2, len, d) * 1024 + j * 4 + p * 2];

        const int4* hb = (const int4*)&h8[s & 1][0];
        int a0 = 0, c0 = 0, a1 = 0, c1 = 0;
        #pragma unroll
        for (int kc = 0; kc < 16; kc++) {
            int4 hv = hb[kc];   // wave-uniform -> LDS broadcast
            a0 = dot4(aread(wa[kc * 4 + 0]), hv.x, a0);
            c0 = dot4(aread(wa[kc * 4 + 1]), hv.y, c0);
            a0 = dot4(aread(wa[kc * 4 + 2]), hv.z, a0);
            c0 = dot4(aread(wa[kc * 4 + 3]), hv.w, c0);
            a1 = dot4(aread(wb[kc * 4 + 0]), hv.x, a1);
            c1 = dot4(aread(wb[kc * 4 + 1]), hv.y, c1);
            a1 = dot4(aread(wb[kc * 4 + 2]), hv.z, a1);
            c1 = dot4(aread(wb[kc * 4 + 3]), hv.w, c1);
        }
        float pre0 = bf2f((ushort_t)(xc & 0xffffu)) + fr.x * (float)(a0 + c0);
        float pre1 = bf2f((ushort_t)(xc >> 16))     + fr.y * (float)(a1 + c1);

        if (p) {                       // wave-uniform branch (waves 4..7)
            gA[j] = ftanh(pre0);       // gate g
            oA[j] = fsig(pre1);        // gate o
        }
        lds_barrier();
        if (!p) {                      // waves 0..3
            float ig = fsig(pre0), fg = fsig(pre1);
            c_state = fg * c_state + ig * gA[j];
            float h = oA[j] * ftanh(c_state);
            int t = time_idx(s, len, d);
            out[((size_t)b * 512 + t) * 512 + d * 256 + j] = h;
            int q = __float2int_rn(h * 127.0f);
            q = min(127, max(-127, q));
            ((char*)&h8[1 - (s & 1)][0])[j] = (char)q;
        }
        xv1 = xn;
        lds_barrier();
    }
}

// ---------------------------------------------------------------------------
extern "C" void kernel_launch(void* const* d_in, const int* in_sizes, int n_in,
                              void* d_out, int out_size, void* d_ws, size_t ws_size,
                              hipStream_t stream) {
    (void)in_sizes; (void)n_in; (void)out_size;
    const float* x    = (const float*)d_in[0];
    const int*   lens = (const int*)d_in[1];
    const float* wihf = (const float*)d_in[2];
    const float* whhf = (const float*)d_in[3];
    const float* bihf = (const float*)d_in[4];
    const float* bhhf = (const float*)d_in[5];
    const float* wihb = (const float*)d_in[6];
    const float* whhb = (const float*)d_in[7];
    const float* bihb = (const float*)d_in[8];
    const float* bhhb = (const float*)d_in[9];
    float* out = (float*)d_out;

    char* ws = (char*)d_ws;
    ushort_t* xbf    = (ushort_t*)(ws + 0);          //  16,777,216 B
    ushort_t* wihbf  = (ushort_t*)(ws + 16777216);   //   1,048,576 B
    float*    biasv  = (float*)(ws + 17825792);      //       8,192 B
    int*      wq4    = (int*)(ws + 17833984);        //     524,288 B
    float*    fscale4= (float*)(ws + 18358272);      //       8,192 B
    ushort_t* xproj  = (ushort_t*)(ws + 18366464);   // 134,217,728 B
    const size_t REQ = 18366464 + 134217728ull;
    if (ws_size < REQ) {
        fprintf(stderr, "kernel_launch: ws too small: %zu < %zu\n", ws_size, REQ);
    }

    k_f2bf<<<8192, 256, 0, stream>>>(x, xbf, 8388608);
    k_wih<<<dim3(256, 2), 256, 0, stream>>>(wihf, wihb, wihbf);
    k_bias<<<8, 256, 0, stream>>>(bihf, bhhf, bihb, bhhb, biasv);
    k_quant<<<512, 256, 0, stream>>>(whhf, whhb, wq4, fscale4);
    k_gemm<<<dim3(8, 256, 2), 256, 0, stream>>>(xbf, wihbf, biasv, xproj);
    k_rec<<<dim3(64, 2), 512, 0, stream>>>(xproj, wq4, fscale4, lens, out);
}

// Round 7
// 815.184 us; speedup vs baseline: 1.1047x; 1.1047x over previous
//
#include <hip/hip_runtime.h>
#include <cstdio>

// ---------------------------------------------------------------------------
// BiLSTM  B=64, T=512, D=256, H=256
//   P0: x -> bf16; Wih -> bf16 gate-permuted rows; permuted biases;
//       Whh -> int8 wq4[d][kc][j][gate]
//   P1: MFMA bf16 GEMM -> xproj[d][b*512+t][j*4+gate] (bf16)
//   P2: recurrence: 128 WGs (64 batch x 2 dir) x 512 thr. Thread (p,j) owns
//       gate rows {2p,2p+1} of unit j: 128 int8-packed dwords parked in
//       PHYSICAL AGPRs a0..a127 (hard-coded names + clobbers). R1-R6 lesson:
//       any loop-crossing SSA live set gets spilled to scratch by RA no
//       matter the budget; physical regs have no RA-managed live range, so
//       nothing can be spilled. Per-step: 128 v_accvgpr_read + 128 v_dot4.
//       h int8 in double-buffered LDS; lgkm-only barriers.
// ---------------------------------------------------------------------------

typedef unsigned short ushort_t;
typedef __attribute__((ext_vector_type(8))) short short8;
typedef __attribute__((ext_vector_type(4))) float f32x4;

__device__ __forceinline__ ushort_t f2bf(float f) {
    union { float f; unsigned u; } v; v.f = f;
    unsigned r = v.u + 0x7fffu + ((v.u >> 16) & 1u);
    return (ushort_t)(r >> 16);
}
__device__ __forceinline__ float bf2f(ushort_t h) {
    union { unsigned u; float f; } v; v.u = ((unsigned)h) << 16;
    return v.f;
}

__device__ __forceinline__ float fexp2(float x) {
#if __has_builtin(__builtin_amdgcn_exp2f)
    return __builtin_amdgcn_exp2f(x);
#else
    return exp2f(x);
#endif
}
__device__ __forceinline__ float frcp(float x) {
#if __has_builtin(__builtin_amdgcn_rcpf)
    return __builtin_amdgcn_rcpf(x);
#else
    return 1.0f / x;
#endif
}
__device__ __forceinline__ float fsig(float x) {
    return frcp(1.0f + fexp2(-1.44269504089f * x));
}
__device__ __forceinline__ float ftanh(float x) {
    float e = fexp2(2.88539008178f * x);
    return 1.0f - 2.0f * frcp(e + 1.0f);
}

__device__ __forceinline__ int dot4(int a, int b, int c) {
#if __has_builtin(__builtin_amdgcn_sdot4)
    return __builtin_amdgcn_sdot4(a, b, c, false);
#else
    int r = c;
    r += ((a << 24) >> 24) * ((b << 24) >> 24);
    r += ((a << 16) >> 24) * ((b << 16) >> 24);
    r += ((a << 8) >> 24) * ((b << 8) >> 24);
    r += (a >> 24) * (b >> 24);
    return r;
#endif
}

// Physical-AGPR park / retrieve. aN is a hard-coded register name, so the
// value never exists as an RA-managed loop-crossing live range.
#define APK(idx, src) asm volatile("v_accvgpr_write_b32 a" #idx ", %0" :: "v"(src) : "a" #idx)
#define ARD(dst, idx) asm volatile("v_accvgpr_read_b32 %0, a" #idx : "=v"(dst))

// LDS-only barrier: drain lgkm (LDS ops) but NOT vmcnt.
__device__ __forceinline__ void lds_barrier() {
    asm volatile("s_waitcnt lgkmcnt(0)\n\ts_barrier" ::: "memory");
}

// ---------------------------------------------------------------------------
// P0a: fp32 -> bf16 (n multiple of 4)
__global__ __launch_bounds__(256) void k_f2bf(const float* __restrict__ in,
                                              ushort_t* __restrict__ out, int n) {
    int i = (blockIdx.x * 256 + threadIdx.x) * 4;
    if (i + 3 < n) {
        float4 v = *(const float4*)&in[i];
        ushort4 o;
        o.x = f2bf(v.x); o.y = f2bf(v.y); o.z = f2bf(v.z); o.w = f2bf(v.w);
        *(ushort4*)&out[i] = o;
    }
}

// P0b: Wih fp32 -> bf16 with gate-permuted ROW order:
//   dst[d][(n&255)*4 + (n>>8)][k] = src_d[n][k]
__global__ __launch_bounds__(256) void k_wih(const float* __restrict__ wihf,
                                             const float* __restrict__ wihb,
                                             ushort_t* __restrict__ dst) {
    int d = blockIdx.y;
    int n = blockIdx.x * 4 + (threadIdx.x >> 6);   // 0..1023
    int l = threadIdx.x & 63;
    const float* src = (d ? wihb : wihf) + (size_t)n * 256;
    float4 v = *(const float4*)&src[l * 4];
    int np = (n & 255) * 4 + (n >> 8);
    ushort4 o;
    o.x = f2bf(v.x); o.y = f2bf(v.y); o.z = f2bf(v.z); o.w = f2bf(v.w);
    *(ushort4*)&dst[((size_t)d * 1024 + np) * 256 + l * 4] = o;
}

// P0c: permuted bias vectors bv[d][(n&255)*4 + (n>>8)] = bih_d[n] + bhh_d[n]
__global__ __launch_bounds__(256) void k_bias(const float* __restrict__ bihf,
                                              const float* __restrict__ bhhf,
                                              const float* __restrict__ bihb,
                                              const float* __restrict__ bhhb,
                                              float* __restrict__ bv) {
    int i = blockIdx.x * 256 + threadIdx.x;   // 0..2047
    int d = i >> 10, n = i & 1023;
    float s = d ? (bihb[n] + bhhb[n]) : (bihf[n] + bhhf[n]);
    bv[d * 1024 + (n & 255) * 4 + (n >> 8)] = s;
}

// P0d: quantize Whh rows to int8.
// wq4[d*65536 + kc*1024 + j*4 + gate], kc=k/4, j=row&255, gate=row>>8.
__global__ __launch_bounds__(256) void k_quant(const float* __restrict__ whhf,
                                               const float* __restrict__ whhb,
                                               int* __restrict__ wq4,
                                               float* __restrict__ fscale4) {
    int rowg = blockIdx.x * 4 + (threadIdx.x >> 6);   // 0..2047
    int l = threadIdx.x & 63;                          // = kc
    int d = rowg >> 10;
    int row = rowg & 1023;
    const float* W = (d ? whhb : whhf) + (size_t)row * 256;
    float4 v = *(const float4*)&W[l * 4];
    float m = fmaxf(fmaxf(fabsf(v.x), fabsf(v.y)), fmaxf(fabsf(v.z), fabsf(v.w)));
    #pragma unroll
    for (int off = 32; off > 0; off >>= 1) m = fmaxf(m, __shfl_xor(m, off));
    float inv = (m > 0.0f) ? (127.0f / m) : 0.0f;
    int q0 = __float2int_rn(v.x * inv);
    int q1 = __float2int_rn(v.y * inv);
    int q2 = __float2int_rn(v.z * inv);
    int q3 = __float2int_rn(v.w * inv);
    q0 = min(127, max(-127, q0)); q1 = min(127, max(-127, q1));
    q2 = min(127, max(-127, q2)); q3 = min(127, max(-127, q3));
    int packed = (q0 & 255) | ((q1 & 255) << 8) | ((q2 & 255) << 16) | ((q3 & 255) << 24);
    int j = row & 255, gate = row >> 8;
    wq4[d * 65536 + l * 1024 + j * 4 + gate] = packed;
    if (l == 0) fscale4[d * 1024 + j * 4 + gate] = m / (127.0f * 127.0f);
}

// ---------------------------------------------------------------------------
// P1: bf16 GEMM (contiguous epilogue; B rows pre-permuted).
#define LDSOFF(r, kc) ((r) * 32 + ((((kc) + ((r) >> 1)) & 3) * 8))

__global__ __launch_bounds__(256) void k_gemm(const ushort_t* __restrict__ A,
                                              const ushort_t* __restrict__ Bw,
                                              const float* __restrict__ biasv,
                                              ushort_t* __restrict__ Xp) {
    const int dir = blockIdx.z;
    const ushort_t* Bmat = Bw + dir * 262144;
    const float* bv = biasv + dir * 1024;
    ushort_t* C = Xp + (size_t)dir * 33554432;
    const int tn = blockIdx.x;   // 0..7
    const int tm = blockIdx.y;   // 0..255
    const int tid = threadIdx.x;
    const int w = tid >> 6, l = tid & 63;
    const int wm = w & 1, wn = w >> 1;

    __shared__ ushort_t As[128 * 32];
    __shared__ ushort_t Bs[128 * 32];

    f32x4 acc[4][4];
    #pragma unroll
    for (int i = 0; i < 4; i++)
        #pragma unroll
        for (int jj = 0; jj < 4; jj++) acc[i][jj] = (f32x4){0.f, 0.f, 0.f, 0.f};

    const int r0 = tid >> 2, c0 = tid & 3;
    const int r1 = (tid + 256) >> 2, c1 = tid & 3;

    for (int kb = 0; kb < 8; kb++) {
        __syncthreads();
        {
            short8 a0 = *(const short8*)&A[((size_t)(tm * 128 + r0)) * 256 + kb * 32 + c0 * 8];
            short8 a1 = *(const short8*)&A[((size_t)(tm * 128 + r1)) * 256 + kb * 32 + c1 * 8];
            short8 b0 = *(const short8*)&Bmat[((size_t)(tn * 128 + r0)) * 256 + kb * 32 + c0 * 8];
            short8 b1 = *(const short8*)&Bmat[((size_t)(tn * 128 + r1)) * 256 + kb * 32 + c1 * 8];
            *(short8*)&As[LDSOFF(r0, c0)] = a0;
            *(short8*)&As[LDSOFF(r1, c1)] = a1;
            *(short8*)&Bs[LDSOFF(r0, c0)] = b0;
            *(short8*)&Bs[LDSOFF(r1, c1)] = b1;
        }
        __syncthreads();
        short8 af[4], bfr[4];
        const int q = l >> 4;
        #pragma unroll
        for (int mt = 0; mt < 4; mt++) {
            int rr = wm * 64 + mt * 16 + (l & 15);
            af[mt] = *(const short8*)&As[LDSOFF(rr, q)];
        }
        #pragma unroll
        for (int nt = 0; nt < 4; nt++) {
            int rr = wn * 64 + nt * 16 + (l & 15);
            bfr[nt] = *(const short8*)&Bs[LDSOFF(rr, q)];
        }
        #pragma unroll
        for (int mt = 0; mt < 4; mt++)
            #pragma unroll
            for (int nt = 0; nt < 4; nt++)
                acc[mt][nt] = __builtin_amdgcn_mfma_f32_16x16x32_bf16(
                    af[mt], bfr[nt], acc[mt][nt], 0, 0, 0);
    }
    #pragma unroll
    for (int nt = 0; nt < 4; nt++) {
        int n = tn * 128 + wn * 64 + nt * 16 + (l & 15);
        float bn = bv[n];
        #pragma unroll
        for (int mt = 0; mt < 4; mt++) {
            #pragma unroll
            for (int rr = 0; rr < 4; rr++) {
                int m = tm * 128 + wm * 64 + mt * 16 + (l >> 4) * 4 + rr;
                C[(size_t)m * 1024 + n] = f2bf(acc[mt][nt][rr] + bn);
            }
        }
    }
}

// ---------------------------------------------------------------------------
// P2: recurrence. grid (64 batch, 2 dir) x 512 threads.
// Thread (p = tid>>8, j = tid&255) owns gate rows {2p, 2p+1} of unit j.
// p=0 -> gates i,f (owns c[j], h[j]); p=1 -> gates g,o.
__device__ __forceinline__ int time_idx(int s, int len, int d) {
    int sc = (s < len - 1) ? s : (len - 1);
    return (d == 0) ? sc : (len - 1 - sc);
}

#define LDW(kc) (*(const int2*)&wq[(kc) * 1024 + j4p2])

// chunk c: kc = 4c..4c+3, weight AGPRs a[8c..8c+7] (rowA=even, rowB=odd)
#define CHUNK(c, i0,i1,i2,i3,i4,i5,i6,i7) do { \
    int4 hv_ = hb[c]; int t0_,t1_,t2_,t3_,t4_,t5_,t6_,t7_; \
    ARD(t0_, i0); ARD(t1_, i1); ARD(t2_, i2); ARD(t3_, i3); \
    ARD(t4_, i4); ARD(t5_, i5); ARD(t6_, i6); ARD(t7_, i7); \
    sA0 = dot4(t0_, hv_.x, sA0); sB0 = dot4(t1_, hv_.x, sB0); \
    sA1 = dot4(t2_, hv_.y, sA1); sB1 = dot4(t3_, hv_.y, sB1); \
    sA0 = dot4(t4_, hv_.z, sA0); sB0 = dot4(t5_, hv_.z, sB0); \
    sA1 = dot4(t6_, hv_.w, sA1); sB1 = dot4(t7_, hv_.w, sB1); \
} while (0)

__global__ __launch_bounds__(512, 2)
void k_rec(const ushort_t* __restrict__ xproj,
           const int* __restrict__ wq4,
           const float* __restrict__ fscale4,
           const int* __restrict__ lens,
           float* __restrict__ out) {
    const int b = blockIdx.x, d = blockIdx.y;
    const int tid = threadIdx.x;
    const int j = tid & 255, p = tid >> 8;
    int len = lens[b];
    if (len < 1) len = 1;
    if (len > 512) len = 512;
    const ushort_t* xp = xproj + ((size_t)d * 64 + b) * 524288;  // 512*1024
    const int* wq = wq4 + d * 65536;
    const int j4p2 = j * 4 + p * 2;
    float2 fr = *(const float2*)&fscale4[d * 1024 + j4p2];

    // Park 128 weight dwords into physical AGPRs a0..a127, 8 loads per batch
    // so the global-load latency pipelines (~2us once per kernel).
    { int2 v0=LDW(0),v1=LDW(1),v2=LDW(2),v3=LDW(3),v4=LDW(4),v5=LDW(5),v6=LDW(6),v7=LDW(7);
      APK(0,v0.x); APK(1,v0.y); APK(2,v1.x); APK(3,v1.y); APK(4,v2.x); APK(5,v2.y); APK(6,v3.x); APK(7,v3.y);
      APK(8,v4.x); APK(9,v4.y); APK(10,v5.x); APK(11,v5.y); APK(12,v6.x); APK(13,v6.y); APK(14,v7.x); APK(15,v7.y); }
    { int2 v0=LDW(8),v1=LDW(9),v2=LDW(10),v3=LDW(11),v4=LDW(12),v5=LDW(13),v6=LDW(14),v7=LDW(15);
      APK(16,v0.x); APK(17,v0.y); APK(18,v1.x); APK(19,v1.y); APK(20,v2.x); APK(21,v2.y); APK(22,v3.x); APK(23,v3.y);
      APK(24,v4.x); APK(25,v4.y); APK(26,v5.x); APK(27,v5.y); APK(28,v6.x); APK(29,v6.y); APK(30,v7.x); APK(31,v7.y); }
    { int2 v0=LDW(16),v1=LDW(17),v2=LDW(18),v3=LDW(19),v4=LDW(20),v5=LDW(21),v6=LDW(22),v7=LDW(23);
      APK(32,v0.x); APK(33,v0.y); APK(34,v1.x); APK(35,v1.y); APK(36,v2.x); APK(37,v2.y); APK(38,v3.x); APK(39,v3.y);
      APK(40,v4.x); APK(41,v4.y); APK(42,v5.x); APK(43,v5.y); APK(44,v6.x); APK(45,v6.y); APK(46,v7.x); APK(47,v7.y); }
    { int2 v0=LDW(24),v1=LDW(25),v2=LDW(26),v3=LDW(27),v4=LDW(28),v5=LDW(29),v6=LDW(30),v7=LDW(31);
      APK(48,v0.x); APK(49,v0.y); APK(50,v1.x); APK(51,v1.y); APK(52,v2.x); APK(53,v2.y); APK(54,v3.x); APK(55,v3.y);
      APK(56,v4.x); APK(57,v4.y); APK(58,v5.x); APK(59,v5.y); APK(60,v6.x); APK(61,v6.y); APK(62,v7.x); APK(63,v7.y); }
    { int2 v0=LDW(32),v1=LDW(33),v2=LDW(34),v3=LDW(35),v4=LDW(36),v5=LDW(37),v6=LDW(38),v7=LDW(39);
      APK(64,v0.x); APK(65,v0.y); APK(66,v1.x); APK(67,v1.y); APK(68,v2.x); APK(69,v2.y); APK(70,v3.x); APK(71,v3.y);
      APK(72,v4.x); APK(73,v4.y); APK(74,v5.x); APK(75,v5.y); APK(76,v6.x); APK(77,v6.y); APK(78,v7.x); APK(79,v7.y); }
    { int2 v0=LDW(40),v1=LDW(41),v2=LDW(42),v3=LDW(43),v4=LDW(44),v5=LDW(45),v6=LDW(46),v7=LDW(47);
      APK(80,v0.x); APK(81,v0.y); APK(82,v1.x); APK(83,v1.y); APK(84,v2.x); APK(85,v2.y); APK(86,v3.x); APK(87,v3.y);
      APK(88,v4.x); APK(89,v4.y); APK(90,v5.x); APK(91,v5.y); APK(92,v6.x); APK(93,v6.y); APK(94,v7.x); APK(95,v7.y); }
    { int2 v0=LDW(48),v1=LDW(49),v2=LDW(50),v3=LDW(51),v4=LDW(52),v5=LDW(53),v6=LDW(54),v7=LDW(55);
      APK(96,v0.x); APK(97,v0.y); APK(98,v1.x); APK(99,v1.y); APK(100,v2.x); APK(101,v2.y); APK(102,v3.x); APK(103,v3.y);
      APK(104,v4.x); APK(105,v4.y); APK(106,v5.x); APK(107,v5.y); APK(108,v6.x); APK(109,v6.y); APK(110,v7.x); APK(111,v7.y); }
    { int2 v0=LDW(56),v1=LDW(57),v2=LDW(58),v3=LDW(59),v4=LDW(60),v5=LDW(61),v6=LDW(62),v7=LDW(63);
      APK(112,v0.x); APK(113,v0.y); APK(114,v1.x); APK(115,v1.y); APK(116,v2.x); APK(117,v2.y); APK(118,v3.x); APK(119,v3.y);
      APK(120,v4.x); APK(121,v4.y); APK(122,v5.x); APK(123,v5.y); APK(124,v6.x); APK(125,v6.y); APK(126,v7.x); APK(127,v7.y); }

    __shared__ int h8[2][64] __attribute__((aligned(16)));
    __shared__ float gA[256], oA[256];
    if (tid < 64) h8[0][tid] = 0;

    // zero-fill this direction's half for t in [len, 512)
    {
        float4 z = {0.f, 0.f, 0.f, 0.f};
        int total4 = (512 - len) * 64;
        for (int i = tid; i < total4; i += 512) {
            int t = len + (i >> 6);
            int c4 = i & 63;
            *(float4*)&out[((size_t)b * 512 + t) * 512 + d * 256 + c4 * 4] = z;
        }
    }
    __syncthreads();

    float c_state = 0.0f;
    unsigned xv0 = *(const unsigned*)&xp[(size_t)time_idx(0, len, d) * 1024 + j4p2];
    unsigned xv1 = *(const unsigned*)&xp[(size_t)time_idx(1, len, d) * 1024 + j4p2];

    for (int s = 0; s < len; s++) {
        unsigned xc = xv0;
        xv0 = xv1;
        unsigned xn = *(const unsigned*)&xp[(size_t)time_idx(s + 2, len, d) * 1024 + j4p2];

        const int4* hb = (const int4*)&h8[s & 1][0];
        int sA0 = 0, sA1 = 0, sB0 = 0, sB1 = 0;
        CHUNK(0,   0,  1,  2,  3,  4,  5,  6,  7);
        CHUNK(1,   8,  9, 10, 11, 12, 13, 14, 15);
        CHUNK(2,  16, 17, 18, 19, 20, 21, 22, 23);
        CHUNK(3,  24, 25, 26, 27, 28, 29, 30, 31);
        CHUNK(4,  32, 33, 34, 35, 36, 37, 38, 39);
        CHUNK(5,  40, 41, 42, 43, 44, 45, 46, 47);
        CHUNK(6,  48, 49, 50, 51, 52, 53, 54, 55);
        CHUNK(7,  56, 57, 58, 59, 60, 61, 62, 63);
        CHUNK(8,  64, 65, 66, 67, 68, 69, 70, 71);
        CHUNK(9,  72, 73, 74, 75, 76, 77, 78, 79);
        CHUNK(10, 80, 81, 82, 83, 84, 85, 86, 87);
        CHUNK(11, 88, 89, 90, 91, 92, 93, 94, 95);
        CHUNK(12, 96, 97, 98, 99,100,101,102,103);
        CHUNK(13,104,105,106,107,108,109,110,111);
        CHUNK(14,112,113,114,115,116,117,118,119);
        CHUNK(15,120,121,122,123,124,125,126,127);

        float pre0 = bf2f((ushort_t)(xc & 0xffffu)) + fr.x * (float)(sA0 + sA1);
        float pre1 = bf2f((ushort_t)(xc >> 16))     + fr.y * (float)(sB0 + sB1);

        if (p) {                       // waves 4..7: gates g,o
            gA[j] = ftanh(pre0);
            oA[j] = fsig(pre1);
        }
        lds_barrier();
        if (!p) {                      // waves 0..3: gates i,f + state update
            float ig = fsig(pre0), fg = fsig(pre1);
            c_state = fg * c_state + ig * gA[j];
            float h = oA[j] * ftanh(c_state);
            int t = time_idx(s, len, d);
            out[((size_t)b * 512 + t) * 512 + d * 256 + j] = h;
            int q = __float2int_rn(h * 127.0f);
            q = min(127, max(-127, q));
            ((char*)&h8[1 - (s & 1)][0])[j] = (char)q;
        }
        xv1 = xn;
        lds_barrier();
    }
}

// ---------------------------------------------------------------------------
extern "C" void kernel_launch(void* const* d_in, const int* in_sizes, int n_in,
                              void* d_out, int out_size, void* d_ws, size_t ws_size,
                              hipStream_t stream) {
    (void)in_sizes; (void)n_in; (void)out_size;
    const float* x    = (const float*)d_in[0];
    const int*   lens = (const int*)d_in[1];
    const float* wihf = (const float*)d_in[2];
    const float* whhf = (const float*)d_in[3];
    const float* bihf = (const float*)d_in[4];
    const float* bhhf = (const float*)d_in[5];
    const float* wihb = (const float*)d_in[6];
    const float* whhb = (const float*)d_in[7];
    const float* bihb = (const float*)d_in[8];
    const float* bhhb = (const float*)d_in[9];
    float* out = (float*)d_out;

    char* ws = (char*)d_ws;
    ushort_t* xbf    = (ushort_t*)(ws + 0);          //  16,777,216 B
    ushort_t* wihbf  = (ushort_t*)(ws + 16777216);   //   1,048,576 B
    float*    biasv  = (float*)(ws + 17825792);      //       8,192 B
    int*      wq4    = (int*)(ws + 17833984);        //     524,288 B
    float*    fscale4= (float*)(ws + 18358272);      //       8,192 B
    ushort_t* xproj  = (ushort_t*)(ws + 18366464);   // 134,217,728 B
    const size_t REQ = 18366464 + 134217728ull;
    if (ws_size < REQ) {
        fprintf(stderr, "kernel_launch: ws too small: %zu < %zu\n", ws_size, REQ);
    }

    k_f2bf<<<8192, 256, 0, stream>>>(x, xbf, 8388608);
    k_wih<<<dim3(256, 2), 256, 0, stream>>>(wihf, wihb, wihbf);
    k_bias<<<8, 256, 0, stream>>>(bihf, bhhf, bihb, bhhb, biasv);
    k_quant<<<512, 256, 0, stream>>>(whhf, whhb, wq4, fscale4);
    k_gemm<<<dim3(8, 256, 2), 256, 0, stream>>>(xbf, wihbf, biasv, xproj);
    k_rec<<<dim3(64, 2), 512, 0, stream>>>(xproj, wq4, fscale4, lens, out);
}